// Round 13
// baseline (113.613 us; speedup 1.0000x reference)
//
#include <hip/hip_runtime.h>
#include <math.h>

#define KS 11
#define CHUNK 22      // output rows per block = 2 x 11 (ring phases static)
#define GRIDY 24      // 24*22 = 528 >= 512; tail rows masked out of the sum
#define IMW 512
#define IMH 512

struct G11 { float g[KS]; };

typedef int   v4i __attribute__((ext_vector_type(4)));
typedef float f2  __attribute__((ext_vector_type(2)));
typedef float f4  __attribute__((ext_vector_type(4)));

// CK-style direct binding to the raw buffer load intrinsic.
__device__ f4 raw_buf_load_v4(v4i srsrc, int voffset, int soffset, int aux)
    __asm("llvm.amdgcn.raw.buffer.load.v4f32");

// SRD over ONE image row. nrec = IMW*4 for valid rows, 0 for out-of-image
// rows (every load returns 0 -> vertical zero-padding, branchless).
// Horizontal zero-padding: per-dword bounds checks (negative offsets are
// huge-unsigned -> OOB -> 0; offsets >= nrec -> 0). All chunks are 16B-
// aligned, so each chunk is wholly negative or wholly >= 0.
__device__ inline v4i make_row_srd(const float* row, int nrec) {
    union { const float* p; unsigned u[2]; } a; a.p = row;
    v4i r;
    r.x = (int)a.u[0];
    r.y = (int)a.u[1];
    r.z = nrec;             // num_records (bytes, stride==0)
    r.w = 0x00020000;       // raw untyped dword access
    return r;
}

__device__ inline f2 ffma2(f2 a, f2 b, f2 c) {
    return __builtin_elementwise_fma(a, b, c);
}

// One staged input row: 16 floats per image from the 16B-ALIGNED base
// covering the 11-tap window (phase folded into per-lane weights).
struct Row { f4 P0, P1, P2, P3, T0, T1, T2, T3; };

__device__ __forceinline__ Row load_row(const float* pimg, const float* timg,
                                        int yi, int vb) {
    const int nrec = ((unsigned)yi < (unsigned)IMH) ? (IMW * 4) : 0;
    const int yc = yi < 0 ? 0 : (yi > IMH - 1 ? IMH - 1 : yi);
    const v4i ps = make_row_srd(pimg + (size_t)yc * IMW, nrec);
    const v4i ts = make_row_srd(timg + (size_t)yc * IMW, nrec);
    Row r;
    r.P0 = raw_buf_load_v4(ps, vb,      0, 0);
    r.P1 = raw_buf_load_v4(ps, vb + 16, 0, 0);
    r.P2 = raw_buf_load_v4(ps, vb + 32, 0, 0);
    r.P3 = raw_buf_load_v4(ps, vb + 48, 0, 0);
    r.T0 = raw_buf_load_v4(ts, vb,      0, 0);
    r.T1 = raw_buf_load_v4(ts, vb + 16, 0, 0);
    r.T2 = raw_buf_load_v4(ts, vb + 32, 0, 0);
    r.T3 = raw_buf_load_v4(ts, vb + 48, 0, 0);
    return r;
}

// Horizontal conv: 16 aligned taps x per-lane weights (zeros outside the
// 11-tap window), pair-packed f32 on the natural dwordx4 halves.
__device__ __forceinline__ void hconv(const Row& r, const f2* W,
                                      f2& oA, f2& oB, float& oC) {
    const f2 p0 = __builtin_shufflevector(r.P0, r.P0, 0, 1);
    const f2 p1 = __builtin_shufflevector(r.P0, r.P0, 2, 3);
    const f2 p2 = __builtin_shufflevector(r.P1, r.P1, 0, 1);
    const f2 p3 = __builtin_shufflevector(r.P1, r.P1, 2, 3);
    const f2 p4 = __builtin_shufflevector(r.P2, r.P2, 0, 1);
    const f2 p5 = __builtin_shufflevector(r.P2, r.P2, 2, 3);
    const f2 p6 = __builtin_shufflevector(r.P3, r.P3, 0, 1);
    const f2 p7 = __builtin_shufflevector(r.P3, r.P3, 2, 3);
    const f2 t0 = __builtin_shufflevector(r.T0, r.T0, 0, 1);
    const f2 t1 = __builtin_shufflevector(r.T0, r.T0, 2, 3);
    const f2 t2 = __builtin_shufflevector(r.T1, r.T1, 0, 1);
    const f2 t3 = __builtin_shufflevector(r.T1, r.T1, 2, 3);
    const f2 t4 = __builtin_shufflevector(r.T2, r.T2, 0, 1);
    const f2 t5 = __builtin_shufflevector(r.T2, r.T2, 2, 3);
    const f2 t6 = __builtin_shufflevector(r.T3, r.T3, 0, 1);
    const f2 t7 = __builtin_shufflevector(r.T3, r.T3, 2, 3);
    const f2 wp0 = W[0] * p0, wp1 = W[1] * p1, wp2 = W[2] * p2, wp3 = W[3] * p3;
    const f2 wp4 = W[4] * p4, wp5 = W[5] * p5, wp6 = W[6] * p6, wp7 = W[7] * p7;
    const f2 wt0 = W[0] * t0, wt1 = W[1] * t1, wt2 = W[2] * t2, wt3 = W[3] * t3;
    const f2 wt4 = W[4] * t4, wt5 = W[5] * t5, wt6 = W[6] * t6, wt7 = W[7] * t7;
    const f2 v0 = ((wp0 + wp1) + (wp2 + wp3)) + ((wp4 + wp5) + (wp6 + wp7));
    const f2 v1 = ((wt0 + wt1) + (wt2 + wt3)) + ((wt4 + wt5) + (wt6 + wt7));
    const f2 v2 = ffma2(wp0, p0, ffma2(wp1, p1, ffma2(wp2, p2, ffma2(wp3, p3,
                   ffma2(wp4, p4, ffma2(wp5, p5, ffma2(wp6, p6, wp7 * p7)))))));
    const f2 v3 = ffma2(wt0, t0, ffma2(wt1, t1, ffma2(wt2, t2, ffma2(wt3, t3,
                   ffma2(wt4, t4, ffma2(wt5, t5, ffma2(wt6, t6, wt7 * t7)))))));
    const f2 v4 = ffma2(wp0, t0, ffma2(wp1, t1, ffma2(wp2, t2, ffma2(wp3, t3,
                   ffma2(wp4, t4, ffma2(wp5, t5, ffma2(wp6, t6, wp7 * t7)))))));
    oA = (f2){v0.x + v0.y, v1.x + v1.y};
    oB = (f2){v2.x + v2.y, v3.x + v3.y};
    oC = v4.x + v4.y;
}

// g[idx] with compile-time-safe clamped access; 0 outside [0,10].
#define GW(idx) (((idx) >= 0 && (idx) <= 10)                                 \
                     ? gw.g[(idx) < 0 ? 0 : ((idx) > 10 ? 10 : (idx))] : 0.f)

// Each thread owns one output column x and streams CHUNK rows downward.
// Rotated pipeline per step k: issue aligned loads(row k+6) -> vertical +
// SSIM for output k -> h-conv the staged row into the ring.
__global__ __launch_bounds__(256, 1) void ssim_col_kernel(
    const float* __restrict__ pred, const float* __restrict__ target,
    float* __restrict__ partial, G11 gw)
{
    const int tid = threadIdx.x;
    const int x   = blockIdx.x * 256 + tid;       // output column, 0..511
    const int y0  = blockIdx.y * CHUNK;           // first output row
    const int bc  = blockIdx.z;
    const float* pimg = pred   + (size_t)bc * (IMH * IMW);
    const float* timg = target + (size_t)bc * (IMH * IMW);

    // 16B-aligned window base (column & byte); phase folded into weights
    const int vbc = (x - 6) & ~3;                 // may be negative
    const int vb  = vbc * 4;                      // 16B-aligned byte offset
    const int ph  = (x - 6) & 3;                  // 0..3, per-lane

    // one-time per-lane weight table: element i has weight g[i-ph-1]
    f2 W[8];
    #pragma unroll
    for (int i = 0; i < 16; i += 2) {
        const float l0 = GW(i - 1), h0 = GW(i);
        const float l1 = GW(i - 2), h1 = GW(i - 1);
        const float l2 = GW(i - 3), h2 = GW(i - 2);
        const float l3 = GW(i - 4), h3 = GW(i - 3);
        const float lo = ph == 0 ? l0 : (ph == 1 ? l1 : (ph == 2 ? l2 : l3));
        const float hi = ph == 0 ? h0 : (ph == 1 ? h1 : (ph == 2 ? h2 : h3));
        W[i / 2] = (f2){lo, hi};
    }

    // ring: hA = {h(p),h(t)}, hB = {h(p^2),h(t^2)}, hc = h(pt)
    f2    hA[KS], hB[KS];
    float hc[KS];

    // Prologue: ingest input rows y0-5 .. y0+5 into slots 0..10.
    #pragma unroll
    for (int i = 0; i < KS; ++i) {
        Row r = load_row(pimg, timg, y0 - 5 + i, vb);
        hconv(r, W, hA[i], hB[i], hc[i]);
    }

    const float C1 = 1e-4f, C2 = 9e-4f;
    float acc = 0.f;

    // Main: step k ingests row y0+k+6 into slot k%11 == kk; vertical tap j
    // reads slot (kk+j)%11 (k0 % 11 == 0, all compile-time).
    for (int k0 = 0; k0 < CHUNK; k0 += KS) {
        #pragma unroll
        for (int kk = 0; kk < KS; ++kk) {
            const int k = k0 + kk;

            // 1) issue next ingest row's aligned loads (consumed in step 3)
            Row r = load_row(pimg, timg, y0 + k + 6, vb);

            // 2) vertical + SSIM for output row y0+k (ring is complete)
            f2 M = {0.f, 0.f}, S2 = {0.f, 0.f};
            float s12 = 0.f;
            #pragma unroll
            for (int j = 0; j < KS; ++j) {
                const f2 w2 = {gw.g[j], gw.g[j]};
                M   = ffma2(w2, hA[(kk + j) % KS], M);
                S2  = ffma2(w2, hB[(kk + j) % KS], S2);
                s12 = fmaf(gw.g[j], hc[(kk + j) % KS], s12);
            }
            const float m1 = M.x, m2 = M.y;
            const float mu1s = m1 * m1, mu2s = m2 * m2, mu12 = m1 * m2;
            const float sg1  = S2.x - mu1s;
            const float sg2  = S2.y - mu2s;
            const float sg12 = s12 - mu12;
            const float num = (2.f * mu12 + C1) * (2.f * sg12 + C2);
            const float den = (mu1s + mu2s + C1) * (sg1 + sg2 + C2);
            const float val = num * __builtin_amdgcn_rcpf(den);
            // mask output rows beyond the image (block y=23 covers 506..527)
            acc += (y0 + k < IMH) ? val : 0.f;

            // 3) h-conv the staged row into slot kk (WAR keeps ordering)
            hconv(r, W, hA[kk], hB[kk], hc[kk]);
        }
    }

    // Block reduction: wave shfl, then cross-wave via tiny LDS.
    __shared__ float wsum[4];
    #pragma unroll
    for (int off = 32; off > 0; off >>= 1) acc += __shfl_down(acc, off, 64);
    const int wid = tid >> 6, lane = tid & 63;
    if (lane == 0) wsum[wid] = acc;
    __syncthreads();
    if (tid == 0) {
        atomicAdd(partial, wsum[0] + wsum[1] + wsum[2] + wsum[3]);
    }
}

__global__ void ssim_final_kernel(const float* __restrict__ partial,
                                  float* __restrict__ out, float invN)
{
    out[0] = 1.f - partial[0] * invN;
}

extern "C" void kernel_launch(void* const* d_in, const int* in_sizes, int n_in,
                              void* d_out, int out_size, void* d_ws, size_t ws_size,
                              hipStream_t stream) {
    const float* pred   = (const float*)d_in[0];
    const float* target = (const float*)d_in[1];
    float* out = (float*)d_out;
    float* partial = (float*)d_ws;

    const int B = 16, C = 3;
    const float invN = 1.0f / ((float)B * C * IMH * IMW);

    // separable 1-D Gaussian, same formula as reference (sigma=1.5, 11 taps)
    G11 gw;
    {
        float s = 0.f;
        for (int i = 0; i < KS; ++i) {
            double e = exp(-((double)((i - 5) * (i - 5))) / (2.0 * 1.5 * 1.5));
            gw.g[i] = (float)e;
            s += gw.g[i];
        }
        for (int i = 0; i < KS; ++i) gw.g[i] /= s;
    }

    hipMemsetAsync(partial, 0, sizeof(float), stream);

    dim3 grid(IMW / 256, GRIDY, B * C);   // 2 x 24 x 48 = 2304 blocks
    dim3 block(256);
    ssim_col_kernel<<<grid, block, 0, stream>>>(pred, target, partial, gw);
    ssim_final_kernel<<<1, 1, 0, stream>>>(partial, out, invN);
}

// Round 14
// 88.466 us; speedup vs baseline: 1.2843x; 1.2843x over previous
//
#include <hip/hip_runtime.h>
#include <math.h>

#define KS 11
#define CHUNK 44      // output rows per block; 2 x 22 steps (lcm(2,11) static phases)
#define GRIDY 12      // 12*44 = 528 >= 512; tail rows masked out of the sum
#define IMW 512
#define IMH 512

struct G11 { float g[KS]; };

typedef int   v4i __attribute__((ext_vector_type(4)));
typedef float f2  __attribute__((ext_vector_type(2)));
typedef float f4  __attribute__((ext_vector_type(4)));

// CK-style direct binding to the raw buffer load intrinsic.
__device__ f2 raw_buf_load_v2(v4i srsrc, int voffset, int soffset, int aux)
    __asm("llvm.amdgcn.raw.buffer.load.v2f32");

// SRD over ONE image row. nrec = IMW*4 for valid rows, 0 for out-of-image
// rows (all loads return 0 -> vertical zero-padding, branchless). Horizontal
// zero-padding: per-dword bounds checks (negative voffset wraps huge-unsigned
// -> OOB -> 0; voffset >= nrec -> 0).
__device__ inline v4i make_row_srd(const float* row, int nrec) {
    union { const float* p; unsigned u[2]; } a; a.p = row;
    v4i r;
    r.x = (int)a.u[0];
    r.y = (int)a.u[1];
    r.z = nrec;             // num_records (bytes, stride==0)
    r.w = 0x00020000;       // raw untyped dword access
    return r;
}

__device__ inline f2 ffma2(f2 a, f2 b, f2 c) {
    return __builtin_elementwise_fma(a, b, c);
}

// g[idx] for compile-time idx, 0 outside [0,10].
#define GW(idx) (((idx) >= 0 && (idx) <= 10)                                 \
                     ? gw.g[(idx) < 0 ? 0 : ((idx) > 10 ? 10 : (idx))] : 0.f)

// Wave-private LDS row cache, no barriers. Each wave owns 64 output columns
// [wx0, wx0+64). Per row: the wave loads the unique 128-col span ONCE
// coalesced (2 x dwordx2 per image pair -> 1KB returned vs 6KB of per-lane
// gathers), ds_write_b128's it as interleaved {p,t} f2 pairs into its own
// double buffer, and each lane reads its 16-col window back as 8 aligned
// ds_read_b128 (4-lane broadcast groups -> conflict-free). The 11-tap phase
// is folded into a per-lane 14-entry weight table (elements 0,15 always 0).
__global__ __launch_bounds__(256, 1) void ssim_col_kernel(
    const float* __restrict__ pred, const float* __restrict__ target,
    float* __restrict__ partial, G11 gw)
{
    const int tid  = threadIdx.x;
    const int wid  = tid >> 6;
    const int lane = tid & 63;
    const int x    = blockIdx.x * 256 + tid;        // output column, 0..511
    const int wx0  = blockIdx.x * 256 + wid * 64;   // wave's first column
    const int y0   = blockIdx.y * CHUNK;            // first output row
    const int bc   = blockIdx.z;
    const float* pimg = pred   + (size_t)bc * (IMH * IMW);
    const float* timg = target + (size_t)bc * (IMH * IMW);

    // [wave][parity][f4 {p,t,p,t} covering cols E+2i, E+2i+1], E = wx0-8
    __shared__ f4 rbuf[4][2][64];      // 8 KiB
    __shared__ float wsum[4];

    // coalesced global byte offset: lane loads cols E+2*lane, E+2*lane+1
    const int vgb = (wx0 - 8 + 2 * lane) * 4;
    // per-lane window: 16 cols starting at c0 (multiple of 4 -> 16B-aligned)
    const int c0  = (x - 6) & ~3;
    const int q0  = (c0 - (wx0 - 8)) >> 1;          // f4 index of window start
    const int ph  = (x - 6) & 3;

    // weight of window element e (1..14) = g[e-1-ph]; elements 0,15 are 0
    float W[14];
    #pragma unroll
    for (int i = 0; i < 14; ++i) {
        const float w0 = GW(i), w1 = GW(i - 1), w2 = GW(i - 2), w3 = GW(i - 3);
        W[i] = ph == 0 ? w0 : (ph == 1 ? w1 : (ph == 2 ? w2 : w3));
    }

    // ring: hA = {h(p),h(t)}, hB = {h(p^2),h(t^2)}, hc = h(pt); slot(row r) =
    // (r - y0 + 5) % 11, all indices compile-time via the unroll phases.
    f2    hA[KS], hB[KS];
    float hc[KS];

#define LOADROW(LP, LT, YI)                                                 \
    {                                                                       \
        const int yi = (YI);                                                \
        const int nrec = ((unsigned)yi < (unsigned)IMH) ? (IMW * 4) : 0;    \
        const int yc = yi < 0 ? 0 : (yi > IMH - 1 ? IMH - 1 : yi);          \
        const v4i ps = make_row_srd(pimg + (size_t)yc * IMW, nrec);         \
        const v4i ts = make_row_srd(timg + (size_t)yc * IMW, nrec);         \
        LP = raw_buf_load_v2(ps, vgb, 0, 0);                                \
        LT = raw_buf_load_v2(ts, vgb, 0, 0);                                \
    }

#define HPAIR(F, WL, WH)                                                    \
    {                                                                       \
        const f2 ptL = __builtin_shufflevector(F, F, 0, 1);                 \
        const f2 ptH = __builtin_shufflevector(F, F, 2, 3);                 \
        const f2 wvL = (f2){(WL), (WL)} * ptL;                              \
        const f2 wvH = (f2){(WH), (WH)} * ptH;                              \
        A = A + wvL + wvH;                                                  \
        Bq = ffma2(wvL, ptL, ffma2(wvH, ptH, Bq));                          \
        Cc = fmaf(wvL.x, ptL.y, fmaf(wvH.x, ptH.y, Cc));                    \
    }

    // read window of the row in parity PAR, h-conv into ring slot S
#define READHCONV(S, PAR)                                                   \
    {                                                                       \
        const f4* rb = &rbuf[wid][PAR][0];                                  \
        const f4 F0 = rb[q0 + 0], F1 = rb[q0 + 1], F2 = rb[q0 + 2];         \
        const f4 F3 = rb[q0 + 3], F4 = rb[q0 + 4], F5 = rb[q0 + 5];         \
        const f4 F6 = rb[q0 + 6], F7 = rb[q0 + 7];                          \
        f2 A, Bq; float Cc;                                                 \
        {   /* element 1 (element 0 has weight 0) */                        \
            const f2 pt = __builtin_shufflevector(F0, F0, 2, 3);            \
            const f2 wv = (f2){W[0], W[0]} * pt;                            \
            A = wv; Bq = wv * pt; Cc = wv.x * pt.y;                         \
        }                                                                   \
        HPAIR(F1, W[1],  W[2])                                              \
        HPAIR(F2, W[3],  W[4])                                              \
        HPAIR(F3, W[5],  W[6])                                              \
        HPAIR(F4, W[7],  W[8])                                              \
        HPAIR(F5, W[9],  W[10])                                             \
        HPAIR(F6, W[11], W[12])                                             \
        {   /* element 14 (element 15 has weight 0) */                      \
            const f2 pt = __builtin_shufflevector(F7, F7, 0, 1);            \
            const f2 wv = (f2){W[13], W[13]} * pt;                          \
            A = A + wv; Bq = ffma2(wv, pt, Bq);                             \
            Cc = fmaf(wv.x, pt.y, Cc);                                      \
        }                                                                   \
        hA[S] = A; hB[S] = Bq; hc[S] = Cc;                                  \
    }

    // Prologue: ingest rows y0-5 .. y0+5 into slots 0..10 (parity (i+1)&1).
    #pragma unroll
    for (int i = 0; i < KS; ++i) {
        f2 lp, lt;
        LOADROW(lp, lt, y0 - 5 + i)
        rbuf[wid][(i + 1) & 1][lane] = (f4){lp.x, lt.x, lp.y, lt.y};
        READHCONV(i, (i + 1) & 1)
    }

    // Preload row y0+6 into staged set A (written by main step 0).
    f2 LpA, LtA, LpB, LtB;
    LOADROW(LpA, LtA, y0 + 6)

    const float C1 = 1e-4f, C2 = 9e-4f;
    float acc = 0.f;

    // Main step k (output row y0+k): load row k+7 into the other staged set;
    // ds_write staged row k+6 (parity k&1); vertical+SSIM for output k (ring
    // complete through row k+5); ds_read row k+6's window, hconv into slot
    // k%11. 22-step unroll keeps ring slot, parity, and reg-set static.
    for (int o = 0; o < 2; ++o) {
        #pragma unroll
        for (int u = 0; u < 22; ++u) {
            const int k = 22 * o + u;

            if ((u & 1) == 0) {
                LOADROW(LpB, LtB, y0 + k + 7)
                rbuf[wid][0][lane] = (f4){LpA.x, LtA.x, LpA.y, LtA.y};
            } else {
                LOADROW(LpA, LtA, y0 + k + 7)
                rbuf[wid][1][lane] = (f4){LpB.x, LtB.x, LpB.y, LtB.y};
            }

            // vertical + SSIM for output row y0+k
            f2 M = {0.f, 0.f}, S2 = {0.f, 0.f};
            float s12 = 0.f;
            #pragma unroll
            for (int j = 0; j < KS; ++j) {
                const f2 w2 = {gw.g[j], gw.g[j]};
                M   = ffma2(w2, hA[(u + j) % KS], M);
                S2  = ffma2(w2, hB[(u + j) % KS], S2);
                s12 = fmaf(gw.g[j], hc[(u + j) % KS], s12);
            }
            const float m1 = M.x, m2 = M.y;
            const float mu1s = m1 * m1, mu2s = m2 * m2, mu12 = m1 * m2;
            const float sg1  = S2.x - mu1s;
            const float sg2  = S2.y - mu2s;
            const float sg12 = s12 - mu12;
            const float num = (2.f * mu12 + C1) * (2.f * sg12 + C2);
            const float den = (mu1s + mu2s + C1) * (sg1 + sg2 + C2);
            const float val = num * __builtin_amdgcn_rcpf(den);
            // mask output rows beyond the image (block y=11 covers 484..527)
            acc += (y0 + k < IMH) ? val : 0.f;

            // ingest row y0+k+6 from the buffer just written (parity u&1)
            READHCONV(u % KS, u & 1)
        }
    }
#undef LOADROW
#undef HPAIR
#undef READHCONV

    // Block reduction: wave shfl, then cross-wave via tiny LDS.
    #pragma unroll
    for (int off = 32; off > 0; off >>= 1) acc += __shfl_down(acc, off, 64);
    if (lane == 0) wsum[wid] = acc;
    __syncthreads();
    if (tid == 0) {
        atomicAdd(partial, wsum[0] + wsum[1] + wsum[2] + wsum[3]);
    }
}

__global__ void ssim_final_kernel(const float* __restrict__ partial,
                                  float* __restrict__ out, float invN)
{
    out[0] = 1.f - partial[0] * invN;
}

extern "C" void kernel_launch(void* const* d_in, const int* in_sizes, int n_in,
                              void* d_out, int out_size, void* d_ws, size_t ws_size,
                              hipStream_t stream) {
    const float* pred   = (const float*)d_in[0];
    const float* target = (const float*)d_in[1];
    float* out = (float*)d_out;
    float* partial = (float*)d_ws;

    const int B = 16, C = 3;
    const float invN = 1.0f / ((float)B * C * IMH * IMW);

    // separable 1-D Gaussian, same formula as reference (sigma=1.5, 11 taps)
    G11 gw;
    {
        float s = 0.f;
        for (int i = 0; i < KS; ++i) {
            double e = exp(-((double)((i - 5) * (i - 5))) / (2.0 * 1.5 * 1.5));
            gw.g[i] = (float)e;
            s += gw.g[i];
        }
        for (int i = 0; i < KS; ++i) gw.g[i] /= s;
    }

    hipMemsetAsync(partial, 0, sizeof(float), stream);

    dim3 grid(IMW / 256, GRIDY, B * C);   // 2 x 12 x 48 = 1152 blocks
    dim3 block(256);
    ssim_col_kernel<<<grid, block, 0, stream>>>(pred, target, partial, gw);
    ssim_final_kernel<<<1, 1, 0, stream>>>(partial, out, invN);
}

// Round 15
// 70.261 us; speedup vs baseline: 1.6170x; 1.2591x over previous
//
#include <hip/hip_runtime.h>
#include <math.h>

#define KS 11
#define CHUNK 44      // output rows per block; 2 x 22 steps (lcm(2,11) static phases)
#define GRIDY 12      // 12*44 = 528 >= 512; tail rows masked out of the sum
#define IMW 512
#define IMH 512

struct G11 { float g[KS]; };

typedef int   v4i __attribute__((ext_vector_type(4)));
typedef float f2  __attribute__((ext_vector_type(2)));
typedef float f4  __attribute__((ext_vector_type(4)));

// CK-style direct binding to the raw buffer load intrinsic.
__device__ f2 raw_buf_load_v2(v4i srsrc, int voffset, int soffset, int aux)
    __asm("llvm.amdgcn.raw.buffer.load.v2f32");

// SRD over ONE image row. nrec = IMW*4 for valid rows, 0 for out-of-image
// rows (all loads return 0 -> vertical zero-padding, branchless). Horizontal
// zero-padding: per-dword bounds checks (negative voffset wraps huge-unsigned
// -> OOB -> 0; voffset >= nrec -> 0). p=t=0 -> s=d=0, so padding survives
// the s/d transform.
__device__ inline v4i make_row_srd(const float* row, int nrec) {
    union { const float* p; unsigned u[2]; } a; a.p = row;
    v4i r;
    r.x = (int)a.u[0];
    r.y = (int)a.u[1];
    r.z = nrec;             // num_records (bytes, stride==0)
    r.w = 0x00020000;       // raw untyped dword access
    return r;
}

__device__ inline f2 ffma2(f2 a, f2 b, f2 c) {
    return __builtin_elementwise_fma(a, b, c);
}

// g[idx] for compile-time idx, 0 outside [0,10].
#define GW(idx) (((idx) >= 0 && (idx) <= 10)                                 \
                     ? gw.g[(idx) < 0 ? 0 : ((idx) > 10 ? 10 : (idx))] : 0.f)

// s/d-transformed SSIM: with s=p+t, d=p-t, only FOUR conv chains are needed
// (h/v of s, d, s^2, d^2):  mu1mu2 = (mus^2-mud^2)/4,  mu1^2+mu2^2 =
// (mus^2+mud^2)/2,  4E[pt] = E[s^2]-E[d^2],  E[p^2]+E[t^2] = (E[s^2]+E[d^2])/2.
// Wave-private LDS row cache (no barriers): per row the wave loads the unique
// 128-col span once coalesced, stores {s,d} interleaved, and each lane reads
// its 16-col window as 8 aligned ds_read_b128. Phase folded into a per-lane
// 14-entry weight table.
__global__ __launch_bounds__(256, 1) void ssim_col_kernel(
    const float* __restrict__ pred, const float* __restrict__ target,
    float* __restrict__ partial, G11 gw)
{
    const int tid  = threadIdx.x;
    const int wid  = tid >> 6;
    const int lane = tid & 63;
    const int x    = blockIdx.x * 256 + tid;        // output column, 0..511
    const int wx0  = blockIdx.x * 256 + wid * 64;   // wave's first column
    const int y0   = blockIdx.y * CHUNK;            // first output row
    const int bc   = blockIdx.z;
    const float* pimg = pred   + (size_t)bc * (IMH * IMW);
    const float* timg = target + (size_t)bc * (IMH * IMW);

    // [wave][parity][f4 {s,d,s,d} covering cols E+2i, E+2i+1], E = wx0-8
    __shared__ f4 rbuf[4][2][64];      // 8 KiB
    __shared__ float wsum[4];

    // coalesced global byte offset: lane loads cols E+2*lane, E+2*lane+1
    const int vgb = (wx0 - 8 + 2 * lane) * 4;
    // per-lane window: 16 cols starting at c0 (multiple of 4 -> 16B-aligned)
    const int c0  = (x - 6) & ~3;
    const int q0  = (c0 - (wx0 - 8)) >> 1;          // f4 index of window start
    const int ph  = (x - 6) & 3;

    // weight of window element e (1..14) = g[e-1-ph]; elements 0,15 are 0
    float W[14];
    #pragma unroll
    for (int i = 0; i < 14; ++i) {
        const float w0 = GW(i), w1 = GW(i - 1), w2 = GW(i - 2), w3 = GW(i - 3);
        W[i] = ph == 0 ? w0 : (ph == 1 ? w1 : (ph == 2 ? w2 : w3));
    }

    // ring: hA = {h(s),h(d)}, hB = {h(s^2),h(d^2)}; slot(row r) =
    // (r - y0 + 5) % 11, all indices compile-time via the unroll phases.
    f2 hA[KS], hB[KS];

#define LOADROW(LP, LT, YI)                                                 \
    {                                                                       \
        const int yi = (YI);                                                \
        const int nrec = ((unsigned)yi < (unsigned)IMH) ? (IMW * 4) : 0;    \
        const int yc = yi < 0 ? 0 : (yi > IMH - 1 ? IMH - 1 : yi);          \
        const v4i ps = make_row_srd(pimg + (size_t)yc * IMW, nrec);         \
        const v4i ts = make_row_srd(timg + (size_t)yc * IMW, nrec);         \
        LP = raw_buf_load_v2(ps, vgb, 0, 0);                                \
        LT = raw_buf_load_v2(ts, vgb, 0, 0);                                \
    }

    // pack two columns of {p,t} into {s0,d0,s1,d1}
#define SDPACK(LP, LT) ((f4){(LP).x + (LT).x, (LP).x - (LT).x,              \
                             (LP).y + (LT).y, (LP).y - (LT).y})

#define HPAIR(F, WL, WH)                                                    \
    {                                                                       \
        const f2 sdL = __builtin_shufflevector(F, F, 0, 1);                 \
        const f2 sdH = __builtin_shufflevector(F, F, 2, 3);                 \
        const f2 wvL = (f2){(WL), (WL)} * sdL;                              \
        const f2 wvH = (f2){(WH), (WH)} * sdH;                              \
        A = A + wvL + wvH;                                                  \
        Bq = ffma2(wvL, sdL, ffma2(wvH, sdH, Bq));                          \
    }

    // read window of the row in parity PAR, h-conv into ring slot S
#define READHCONV(S, PAR)                                                   \
    {                                                                       \
        const f4* rb = &rbuf[wid][PAR][0];                                  \
        const f4 F0 = rb[q0 + 0], F1 = rb[q0 + 1], F2 = rb[q0 + 2];         \
        const f4 F3 = rb[q0 + 3], F4 = rb[q0 + 4], F5 = rb[q0 + 5];         \
        const f4 F6 = rb[q0 + 6], F7 = rb[q0 + 7];                          \
        f2 A, Bq;                                                           \
        {   /* element 1 (element 0 has weight 0) */                        \
            const f2 sd = __builtin_shufflevector(F0, F0, 2, 3);            \
            const f2 wv = (f2){W[0], W[0]} * sd;                            \
            A = wv; Bq = wv * sd;                                           \
        }                                                                   \
        HPAIR(F1, W[1],  W[2])                                              \
        HPAIR(F2, W[3],  W[4])                                              \
        HPAIR(F3, W[5],  W[6])                                              \
        HPAIR(F4, W[7],  W[8])                                              \
        HPAIR(F5, W[9],  W[10])                                             \
        HPAIR(F6, W[11], W[12])                                             \
        {   /* element 14 (element 15 has weight 0) */                      \
            const f2 sd = __builtin_shufflevector(F7, F7, 0, 1);            \
            const f2 wv = (f2){W[13], W[13]} * sd;                          \
            A = A + wv; Bq = ffma2(wv, sd, Bq);                             \
        }                                                                   \
        hA[S] = A; hB[S] = Bq;                                              \
    }

    // Prologue: ingest rows y0-5 .. y0+5 into slots 0..10 (parity (i+1)&1).
    #pragma unroll
    for (int i = 0; i < KS; ++i) {
        f2 lp, lt;
        LOADROW(lp, lt, y0 - 5 + i)
        rbuf[wid][(i + 1) & 1][lane] = SDPACK(lp, lt);
        READHCONV(i, (i + 1) & 1)
    }

    // Preload row y0+6 into staged set A (written by main step 0).
    f2 LpA, LtA, LpB, LtB;
    LOADROW(LpA, LtA, y0 + 6)

    const float C1 = 1e-4f, C2 = 9e-4f;
    float acc = 0.f;

    // Main step k (output row y0+k): load row k+7 into the other staged set;
    // ds_write staged row k+6 (parity k&1); vertical+SSIM for output k (ring
    // complete through row k+5); ds_read row k+6's window, hconv into slot
    // k%11. 22-step unroll keeps ring slot, parity, and reg-set static.
    for (int o = 0; o < 2; ++o) {
        #pragma unroll
        for (int u = 0; u < 22; ++u) {
            const int k = 22 * o + u;

            if ((u & 1) == 0) {
                LOADROW(LpB, LtB, y0 + k + 7)
                rbuf[wid][0][lane] = SDPACK(LpA, LtA);
            } else {
                LOADROW(LpA, LtA, y0 + k + 7)
                rbuf[wid][1][lane] = SDPACK(LpB, LtB);
            }

            // vertical + SSIM for output row y0+k
            f2 M = {0.f, 0.f}, S2 = {0.f, 0.f};
            #pragma unroll
            for (int j = 0; j < KS; ++j) {
                const f2 w2 = {gw.g[j], gw.g[j]};
                M  = ffma2(w2, hA[(u + j) % KS], M);
                S2 = ffma2(w2, hB[(u + j) % KS], S2);
            }
            // reconstruct SSIM terms from s/d moments
            const float mus2 = M.x * M.x, mud2 = M.y * M.y;
            const float A4 = mus2 - mud2;          // 4 mu1 mu2
            const float B2 = mus2 + mud2;          // 2 (mu1^2 + mu2^2)
            const float P4 = S2.x - S2.y;          // 4 E[pt]
            const float Q2 = S2.x + S2.y;          // 2 (E[p^2] + E[t^2])
            const float num = (0.5f * A4 + C1) * (0.5f * (P4 - A4) + C2);
            const float den = (0.5f * B2 + C1) * (0.5f * (Q2 - B2) + C2);
            const float val = num * __builtin_amdgcn_rcpf(den);
            // mask output rows beyond the image (block y=11 covers 484..527)
            acc += (y0 + k < IMH) ? val : 0.f;

            // ingest row y0+k+6 from the buffer just written (parity u&1)
            READHCONV(u % KS, u & 1)
        }
    }
#undef LOADROW
#undef SDPACK
#undef HPAIR
#undef READHCONV

    // Block reduction: wave shfl, then cross-wave via tiny LDS.
    #pragma unroll
    for (int off = 32; off > 0; off >>= 1) acc += __shfl_down(acc, off, 64);
    if (lane == 0) wsum[wid] = acc;
    __syncthreads();
    if (tid == 0) {
        atomicAdd(partial, wsum[0] + wsum[1] + wsum[2] + wsum[3]);
    }
}

__global__ void ssim_final_kernel(const float* __restrict__ partial,
                                  float* __restrict__ out, float invN)
{
    out[0] = 1.f - partial[0] * invN;
}

extern "C" void kernel_launch(void* const* d_in, const int* in_sizes, int n_in,
                              void* d_out, int out_size, void* d_ws, size_t ws_size,
                              hipStream_t stream) {
    const float* pred   = (const float*)d_in[0];
    const float* target = (const float*)d_in[1];
    float* out = (float*)d_out;
    float* partial = (float*)d_ws;

    const int B = 16, C = 3;
    const float invN = 1.0f / ((float)B * C * IMH * IMW);

    // separable 1-D Gaussian, same formula as reference (sigma=1.5, 11 taps)
    G11 gw;
    {
        float s = 0.f;
        for (int i = 0; i < KS; ++i) {
            double e = exp(-((double)((i - 5) * (i - 5))) / (2.0 * 1.5 * 1.5));
            gw.g[i] = (float)e;
            s += gw.g[i];
        }
        for (int i = 0; i < KS; ++i) gw.g[i] /= s;
    }

    hipMemsetAsync(partial, 0, sizeof(float), stream);

    dim3 grid(IMW / 256, GRIDY, B * C);   // 2 x 12 x 48 = 1152 blocks
    dim3 block(256);
    ssim_col_kernel<<<grid, block, 0, stream>>>(pred, target, partial, gw);
    ssim_final_kernel<<<1, 1, 0, stream>>>(partial, out, invN);
}

// Round 16
// 69.522 us; speedup vs baseline: 1.6342x; 1.0106x over previous
//
#include <hip/hip_runtime.h>
#include <math.h>

#define KS 11
#define CHUNK 44      // output rows per block; 2 x 22 steps (lcm(2,11) static phases)
#define GRIDY 12      // 12*44 = 528 >= 512; tail rows masked out of the sum
#define IMW 512
#define IMH 512

// g: 11-tap Gaussian (for the per-lane h-conv table);
// gm = g/sqrt(2) (vertical mean chain), gs = g/2 (vertical second-moment chain)
struct GWargs { float g[KS]; float gm[KS]; float gs[KS]; };

typedef int   v4i __attribute__((ext_vector_type(4)));
typedef float f2  __attribute__((ext_vector_type(2)));
typedef float f4  __attribute__((ext_vector_type(4)));

// CK-style direct binding to the raw buffer load intrinsic.
__device__ f2 raw_buf_load_v2(v4i srsrc, int voffset, int soffset, int aux)
    __asm("llvm.amdgcn.raw.buffer.load.v2f32");

// SRD over ONE image row. nrec = IMW*4 for valid rows, 0 for out-of-image
// rows (all loads return 0 -> vertical zero-padding, branchless). Horizontal
// zero-padding: per-dword bounds checks. p=t=0 -> s=d=0 under the transform.
__device__ inline v4i make_row_srd(const float* row, int nrec) {
    union { const float* p; unsigned u[2]; } a; a.p = row;
    v4i r;
    r.x = (int)a.u[0];
    r.y = (int)a.u[1];
    r.z = nrec;             // num_records (bytes, stride==0)
    r.w = 0x00020000;       // raw untyped dword access
    return r;
}

__device__ inline f2 ffma2(f2 a, f2 b, f2 c) {
    return __builtin_elementwise_fma(a, b, c);
}

// g[idx] for compile-time idx, 0 outside [0,10].
#define GW(idx) (((idx) >= 0 && (idx) <= 10)                                 \
                     ? gw.g[(idx) < 0 ? 0 : ((idx) > 10 ? 10 : (idx))] : 0.f)

// s/d-transformed SSIM (4 conv chains), wave-private LDS row cache with a
// TWO-STEP pipeline: the window read at step k comes from the buffer written
// at step k-1, and this step's ds_write targets the other parity — no
// same-step LDS write->read dependency; the 8 ds_reads are issued before the
// vertical conv and consumed after it (~130 cyc of in-wave cover).
__global__ __launch_bounds__(256, 1) void ssim_col_kernel(
    const float* __restrict__ pred, const float* __restrict__ target,
    float* __restrict__ partial, GWargs gw)
{
    const int tid  = threadIdx.x;
    const int wid  = tid >> 6;
    const int lane = tid & 63;
    const int x    = blockIdx.x * 256 + tid;        // output column, 0..511
    const int wx0  = blockIdx.x * 256 + wid * 64;   // wave's first column
    const int y0   = blockIdx.y * CHUNK;            // first output row
    const int bc   = blockIdx.z;
    const float* pimg = pred   + (size_t)bc * (IMH * IMW);
    const float* timg = target + (size_t)bc * (IMH * IMW);

    // [wave][parity][f4 {s,d,s,d} covering cols E+2i, E+2i+1], E = wx0-8
    __shared__ f4 rbuf[4][2][64];      // 8 KiB
    __shared__ float wsum[4];

    // coalesced global byte offset: lane loads cols E+2*lane, E+2*lane+1
    const int vgb = (wx0 - 8 + 2 * lane) * 4;
    // per-lane window: 16 cols starting at c0 (multiple of 4 -> 16B-aligned)
    const int c0  = (x - 6) & ~3;
    const int q0  = (c0 - (wx0 - 8)) >> 1;          // f4 index of window start
    const int ph  = (x - 6) & 3;

    // weight of window element e (1..14) = g[e-1-ph]; elements 0,15 are 0
    float W[14];
    #pragma unroll
    for (int i = 0; i < 14; ++i) {
        const float w0 = GW(i), w1 = GW(i - 1), w2 = GW(i - 2), w3 = GW(i - 3);
        W[i] = ph == 0 ? w0 : (ph == 1 ? w1 : (ph == 2 ? w2 : w3));
    }

    // ring: hA = {h(s),h(d)}, hB = {h(s^2),h(d^2)}; slot(row r) = (r-y0+5)%11
    f2 hA[KS], hB[KS];

#define LOADROW(LP, LT, YI)                                                 \
    {                                                                       \
        const int yi = (YI);                                                \
        const int nrec = ((unsigned)yi < (unsigned)IMH) ? (IMW * 4) : 0;    \
        const int yc = yi < 0 ? 0 : (yi > IMH - 1 ? IMH - 1 : yi);          \
        const v4i ps = make_row_srd(pimg + (size_t)yc * IMW, nrec);         \
        const v4i ts = make_row_srd(timg + (size_t)yc * IMW, nrec);         \
        LP = raw_buf_load_v2(ps, vgb, 0, 0);                                \
        LT = raw_buf_load_v2(ts, vgb, 0, 0);                                \
    }

    // pack two columns of {p,t} into {s0,d0,s1,d1}
#define SDPACK(LP, LT) ((f4){(LP).x + (LT).x, (LP).x - (LT).x,              \
                             (LP).y + (LT).y, (LP).y - (LT).y})

    // read the 8-f4 window of parity PAR into F0..F7 (locals in scope)
#define READWIN(PAR)                                                        \
        const f4* rb_ = &rbuf[wid][PAR][0];                                 \
        const f4 F0 = rb_[q0 + 0], F1 = rb_[q0 + 1], F2 = rb_[q0 + 2];      \
        const f4 F3 = rb_[q0 + 3], F4 = rb_[q0 + 4], F5 = rb_[q0 + 5];      \
        const f4 F6 = rb_[q0 + 6], F7 = rb_[q0 + 7];

#define HPAIR(F, WL, WH)                                                    \
    {                                                                       \
        const f2 sdL = __builtin_shufflevector(F, F, 0, 1);                 \
        const f2 sdH = __builtin_shufflevector(F, F, 2, 3);                 \
        const f2 wvL = (f2){(WL), (WL)} * sdL;                              \
        const f2 wvH = (f2){(WH), (WH)} * sdH;                              \
        A = A + wvL + wvH;                                                  \
        Bq = ffma2(wvL, sdL, ffma2(wvH, sdH, Bq));                          \
    }

    // h-conv F0..F7 into ring slot S
#define HCONV(S)                                                            \
    {                                                                       \
        f2 A, Bq;                                                           \
        {   /* element 1 (element 0 has weight 0) */                        \
            const f2 sd = __builtin_shufflevector(F0, F0, 2, 3);            \
            const f2 wv = (f2){W[0], W[0]} * sd;                            \
            A = wv; Bq = wv * sd;                                           \
        }                                                                   \
        HPAIR(F1, W[1],  W[2])                                              \
        HPAIR(F2, W[3],  W[4])                                              \
        HPAIR(F3, W[5],  W[6])                                              \
        HPAIR(F4, W[7],  W[8])                                              \
        HPAIR(F5, W[9],  W[10])                                             \
        HPAIR(F6, W[11], W[12])                                             \
        {   /* element 14 (element 15 has weight 0) */                      \
            const f2 sd = __builtin_shufflevector(F7, F7, 0, 1);            \
            const f2 wv = (f2){W[13], W[13]} * sd;                          \
            A = A + wv; Bq = ffma2(wv, sd, Bq);                             \
        }                                                                   \
        hA[S] = A; hB[S] = Bq;                                              \
    }

    // Prologue: rows y0-5 .. y0+5 into slots 0..10 (same-step round trip,
    // one-time cost).
    f2 LpA, LtA, LpB, LtB;
    #pragma unroll
    for (int i = 0; i < KS; ++i) {
        LOADROW(LpA, LtA, y0 - 5 + i)
        rbuf[wid][i & 1][lane] = SDPACK(LpA, LtA);
        { READWIN(i & 1) HCONV(i) }
    }
    // Pipeline priming: buf[0] <- row y0+6 ; regset1 <- row y0+7.
    LOADROW(LpA, LtA, y0 + 6)
    rbuf[wid][0][lane] = SDPACK(LpA, LtA);
    LOADROW(LpB, LtB, y0 + 7)

    const float C1 = 1e-4f, C2 = 9e-4f;
    float acc = 0.f;

    // Main step k (output row y0+k):
    //  1. issue global loads for row k+8 into regset k&1
    //  2. ds_write regset (k+1)&1 (row k+7, loaded last step) -> buf[(k+1)&1]
    //  3. read window of row k+6 from buf[k&1] (written last step) into F
    //  4. vertical + SSIM for output k (covers the reads)
    //  5. h-conv F -> ring slot k%11
    for (int o = 0; o < 2; ++o) {
        #pragma unroll
        for (int u = 0; u < 22; ++u) {
            const int k = 22 * o + u;

            if ((u & 1) == 0) {
                LOADROW(LpA, LtA, y0 + k + 8)
                rbuf[wid][1][lane] = SDPACK(LpB, LtB);
            } else {
                LOADROW(LpB, LtB, y0 + k + 8)
                rbuf[wid][0][lane] = SDPACK(LpA, LtA);
            }

            READWIN(u & 1)

            // vertical with folded scales: gm = g/sqrt2, gs = g/2
            f2 M = {0.f, 0.f}, S2 = {0.f, 0.f};
            #pragma unroll
            for (int j = 0; j < KS; ++j) {
                M  = ffma2((f2){gw.gm[j], gw.gm[j]}, hA[(u + j) % KS], M);
                S2 = ffma2((f2){gw.gs[j], gw.gs[j]}, hB[(u + j) % KS], S2);
            }
            const float xs = M.x * M.x, xd = M.y * M.y;
            const float a  = xs - xd;              // 2 mu1 mu2
            const float b  = xs + xd;              // mu1^2 + mu2^2
            const float p  = S2.x - S2.y;          // 2 E[pt]
            const float q  = S2.x + S2.y;          // E[p^2] + E[t^2]
            const float num = (a + C1) * (p - a + C2);
            const float den = (b + C1) * (q - b + C2);
            const float val = num * __builtin_amdgcn_rcpf(den);
            // mask output rows beyond the image (block y=11 covers 484..527)
            acc += (y0 + k < IMH) ? val : 0.f;

            HCONV(u % KS)
        }
    }
#undef LOADROW
#undef SDPACK
#undef READWIN
#undef HPAIR
#undef HCONV

    // Block reduction: wave shfl, then cross-wave via tiny LDS.
    #pragma unroll
    for (int off = 32; off > 0; off >>= 1) acc += __shfl_down(acc, off, 64);
    if (lane == 0) wsum[wid] = acc;
    __syncthreads();
    if (tid == 0) {
        atomicAdd(partial, wsum[0] + wsum[1] + wsum[2] + wsum[3]);
    }
}

__global__ void ssim_final_kernel(const float* __restrict__ partial,
                                  float* __restrict__ out, float invN)
{
    out[0] = 1.f - partial[0] * invN;
}

extern "C" void kernel_launch(void* const* d_in, const int* in_sizes, int n_in,
                              void* d_out, int out_size, void* d_ws, size_t ws_size,
                              hipStream_t stream) {
    const float* pred   = (const float*)d_in[0];
    const float* target = (const float*)d_in[1];
    float* out = (float*)d_out;
    float* partial = (float*)d_ws;

    const int B = 16, C = 3;
    const float invN = 1.0f / ((float)B * C * IMH * IMW);

    // separable 1-D Gaussian, same formula as reference (sigma=1.5, 11 taps)
    GWargs gw;
    {
        float s = 0.f;
        for (int i = 0; i < KS; ++i) {
            double e = exp(-((double)((i - 5) * (i - 5))) / (2.0 * 1.5 * 1.5));
            gw.g[i] = (float)e;
            s += gw.g[i];
        }
        for (int i = 0; i < KS; ++i) {
            gw.g[i]  /= s;
            gw.gm[i]  = gw.g[i] * 0.70710678118654752f;   // g / sqrt(2)
            gw.gs[i]  = gw.g[i] * 0.5f;                   // g / 2
        }
    }

    hipMemsetAsync(partial, 0, sizeof(float), stream);

    dim3 grid(IMW / 256, GRIDY, B * C);   // 2 x 12 x 48 = 1152 blocks
    dim3 block(256);
    ssim_col_kernel<<<grid, block, 0, stream>>>(pred, target, partial, gw);
    ssim_final_kernel<<<1, 1, 0, stream>>>(partial, out, invN);
}